// Round 1
// baseline (1250.977 us; speedup 1.0000x reference)
//
#include <hip/hip_runtime.h>

#define WW 1280
#define HH 720
#define NB 8
#define NPIX (HH * WW)          // 921600
#define TOTAL (NB * NPIX)       // 7372800

// ---------------------------------------------------------------------------
// Kernel 0: init. out (2*TOTAL floats) = 0, mind = 1e30, cnt = 0.
// ---------------------------------------------------------------------------
__global__ void k_init(float* __restrict__ out, float* __restrict__ mind,
                       float* __restrict__ cnt) {
    int i = blockIdx.x * blockDim.x + threadIdx.x;
    if (i < 2 * TOTAL) out[i] = 0.0f;
    if (i < TOTAL) {
        mind[i] = 1e30f;
        cnt[i]  = 0.0f;
    }
}

// ---------------------------------------------------------------------------
// Kernel 1: scatter-min of depth bits into the 4 bilinear-footprint targets.
// Depth > 0 and 1e30 > 0, so signed-int bit ordering == float ordering.
// ---------------------------------------------------------------------------
__global__ void k_min(const float* __restrict__ flow,
                      const float* __restrict__ depth,
                      int* __restrict__ mind) {
    int i = blockIdx.x * blockDim.x + threadIdx.x;
    if (i >= TOTAL) return;
    int b = i / NPIX;
    int p = i - b * NPIX;
    int y = p / WW;
    int x = p - y * WW;

    float fx = flow[(size_t)b * 2 * NPIX + p];
    float fy = flow[(size_t)b * 2 * NPIX + NPIX + p];
    float d  = depth[i];

    float x2 = (float)x + fx;
    float y2 = (float)y + fy;
    if (!(x2 >= 0.0f && y2 >= 0.0f && x2 <= (float)(WW - 1) && y2 <= (float)(HH - 1)))
        return;

    int xL = min(max((int)floorf(x2), 0), WW - 1);
    int yT = min(max((int)floorf(y2), 0), HH - 1);
    int xR = min(xL + 1, WW - 1);
    int yB = min(yT + 1, HH - 1);

    int base = b * NPIX;
    int db = __float_as_int(d);
    atomicMin(&mind[base + yT * WW + xL], db);
    atomicMin(&mind[base + yT * WW + xR], db);
    atomicMin(&mind[base + yB * WW + xL], db);
    atomicMin(&mind[base + yB * WW + xR], db);
}

// ---------------------------------------------------------------------------
// Kernel 2: gated scatter-add of (-fx, -fy, 1) into targets where this
// source's depth equals the min depth (exact bit compare).
// Duplicated targets at borders intentionally add twice (matches JAX ref).
// ---------------------------------------------------------------------------
__global__ void k_add(const float* __restrict__ flow,
                      const float* __restrict__ depth,
                      const int* __restrict__ mind,
                      float* __restrict__ out,
                      float* __restrict__ cnt) {
    int i = blockIdx.x * blockDim.x + threadIdx.x;
    if (i >= TOTAL) return;
    int b = i / NPIX;
    int p = i - b * NPIX;
    int y = p / WW;
    int x = p - y * WW;

    float fx = flow[(size_t)b * 2 * NPIX + p];
    float fy = flow[(size_t)b * 2 * NPIX + NPIX + p];
    float d  = depth[i];

    float x2 = (float)x + fx;
    float y2 = (float)y + fy;
    if (!(x2 >= 0.0f && y2 >= 0.0f && x2 <= (float)(WW - 1) && y2 <= (float)(HH - 1)))
        return;

    int xL = min(max((int)floorf(x2), 0), WW - 1);
    int yT = min(max((int)floorf(y2), 0), HH - 1);
    int xR = min(xL + 1, WW - 1);
    int yB = min(yT + 1, HH - 1);

    int base = b * NPIX;
    int db = __float_as_int(d);
    float* outx = out + (size_t)b * 2 * NPIX;
    float* outy = outx + NPIX;

    int g;
    g = yT * WW + xL;
    if (mind[base + g] == db) {
        atomicAdd(&outx[g], -fx); atomicAdd(&outy[g], -fy); atomicAdd(&cnt[base + g], 1.0f);
    }
    g = yT * WW + xR;
    if (mind[base + g] == db) {
        atomicAdd(&outx[g], -fx); atomicAdd(&outy[g], -fy); atomicAdd(&cnt[base + g], 1.0f);
    }
    g = yB * WW + xL;
    if (mind[base + g] == db) {
        atomicAdd(&outx[g], -fx); atomicAdd(&outy[g], -fy); atomicAdd(&cnt[base + g], 1.0f);
    }
    g = yB * WW + xR;
    if (mind[base + g] == db) {
        atomicAdd(&outx[g], -fx); atomicAdd(&outy[g], -fy); atomicAdd(&cnt[base + g], 1.0f);
    }
}

// ---------------------------------------------------------------------------
// Kernel 3: finalize — divide accumulated sums by count where count > 0.
// Where count == 0 the output is already exactly 0 from init.
// ---------------------------------------------------------------------------
__global__ void k_fin(float* __restrict__ out, const float* __restrict__ cnt) {
    int i = blockIdx.x * blockDim.x + threadIdx.x;
    if (i >= TOTAL) return;
    int b = i / NPIX;
    int p = i - b * NPIX;
    float c = cnt[i];
    if (c > 0.0f) {
        size_t ox = (size_t)b * 2 * NPIX + p;
        float inv = 1.0f / c;
        out[ox]        *= inv;
        out[ox + NPIX] *= inv;
    }
}

extern "C" void kernel_launch(void* const* d_in, const int* in_sizes, int n_in,
                              void* d_out, int out_size, void* d_ws, size_t ws_size,
                              hipStream_t stream) {
    const float* flow  = (const float*)d_in[0];
    const float* depth = (const float*)d_in[1];
    float* out  = (float*)d_out;
    float* mind = (float*)d_ws;              // TOTAL floats (as int bits after init)
    float* cnt  = mind + TOTAL;              // TOTAL floats

    const int T = 256;
    k_init<<<(2 * TOTAL + T - 1) / T, T, 0, stream>>>(out, mind, cnt);
    k_min <<<(TOTAL + T - 1) / T, T, 0, stream>>>(flow, depth, (int*)mind);
    k_add <<<(TOTAL + T - 1) / T, T, 0, stream>>>(flow, depth, (const int*)mind, out, cnt);
    k_fin <<<(TOTAL + T - 1) / T, T, 0, stream>>>(out, cnt);
}